// Round 1
// baseline (1174.829 us; speedup 1.0000x reference)
//
#include <hip/hip_runtime.h>

#define BB 8
#define ENC_C 64
#define DEC_C 128
#define HH 128
#define WW 128

// ---------------------------------------------------------------------------
// Kernel 1: per (b,h) row — transpose enc to NHWC, compute k = enc@W_enc+b,
//           q = dec@W_dec+b (both NHWC).
// ---------------------------------------------------------------------------
__global__ __launch_bounds__(256) void prep_kernel(
    const float* __restrict__ enc, const float* __restrict__ dec,
    const float* __restrict__ W_enc, const float* __restrict__ b_enc,
    const float* __restrict__ W_dec, const float* __restrict__ b_dec,
    float* __restrict__ q_buf, float* __restrict__ k_buf,
    float* __restrict__ enc_t)
{
  __shared__ float smem[DEC_C * 129];
  const int bh = blockIdx.x;
  const int b = bh >> 7, h = bh & 127;
  const int tid = threadIdx.x;
  const int c = tid & 63;          // lane -> channel
  const int wbase = tid >> 6;      // wave id -> w offset

  // ---- phase 1: encoder tile [64c][128w] ----
  #pragma unroll
  for (int i = 0; i < 32; ++i) {
    int idx = tid + i * 256;
    int cc = idx >> 7, w = idx & 127;
    smem[cc * 129 + w] = enc[((b * ENC_C + cc) * HH + h) * WW + w];
  }
  __syncthreads();

  // write enc_t NHWC
  #pragma unroll
  for (int i = 0; i < 32; ++i) {
    int idx = tid + i * 256;
    int w = idx >> 6, cc = idx & 63;
    enc_t[((long)bh * WW + w) * 64 + cc] = smem[cc * 129 + w];
  }

  // k = enc @ W_enc + b_enc
  {
    float acc[32];
    const float bk = b_enc[c];
    #pragma unroll
    for (int i = 0; i < 32; ++i) acc[i] = bk;
    for (int d = 0; d < 64; ++d) {
      float wgt = W_enc[d * 64 + c];
      #pragma unroll
      for (int i = 0; i < 32; ++i)
        acc[i] += smem[d * 129 + wbase + i * 4] * wgt;
    }
    #pragma unroll
    for (int i = 0; i < 32; ++i)
      k_buf[((long)bh * WW + wbase + i * 4) * 64 + c] = acc[i];
  }
  __syncthreads();

  // ---- phase 2: decoder tile [128d][128w] -> q ----
  #pragma unroll
  for (int i = 0; i < 64; ++i) {
    int idx = tid + i * 256;
    int dd = idx >> 7, w = idx & 127;
    smem[dd * 129 + w] = dec[((b * DEC_C + dd) * HH + h) * WW + w];
  }
  __syncthreads();
  {
    float acc[32];
    const float bq = b_dec[c];
    #pragma unroll
    for (int i = 0; i < 32; ++i) acc[i] = bq;
    for (int d = 0; d < 128; ++d) {
      float wgt = W_dec[d * 64 + c];
      #pragma unroll
      for (int i = 0; i < 32; ++i)
        acc[i] += smem[d * 129 + wbase + i * 4] * wgt;
    }
    #pragma unroll
    for (int i = 0; i < 32; ++i)
      q_buf[((long)bh * WW + wbase + i * 4) * 64 + c] = acc[i];
  }
}

// ---------------------------------------------------------------------------
// Kernel 2: 3x3 SAME conv, DEC(128) -> ENC(64) channels, NCHW input,
//           NHWC f32 output. One thread per w, 64 accumulators.
// ---------------------------------------------------------------------------
__global__ __launch_bounds__(128) void conv_kernel(
    const float* __restrict__ dec, const float* __restrict__ conv_w,
    const float* __restrict__ conv_b, float* __restrict__ vals_buf)
{
  __shared__ float vs[WW * 65];
  const int bh = blockIdx.x;
  const int b = bh >> 7, h = bh & 127;
  const int w = threadIdx.x;

  float acc[64];
  #pragma unroll
  for (int c = 0; c < 64; ++c) acc[c] = conv_b[c];

  for (int d = 0; d < DEC_C; ++d) {
    const float* base = dec + ((long)(b * DEC_C + d) * HH) * WW;
    #pragma unroll
    for (int kh = 0; kh < 3; ++kh) {
      int hh = h + kh - 1;
      if (hh < 0 || hh >= HH) continue;
      #pragma unroll
      for (int kw = 0; kw < 3; ++kw) {
        int ww2 = w + kw - 1;
        float x = (ww2 >= 0 && ww2 < WW) ? base[hh * WW + ww2] : 0.f;
        const float* wp = conv_w + ((kh * 3 + kw) * DEC_C + d) * 64;
        #pragma unroll
        for (int c = 0; c < 64; ++c) acc[c] += x * wp[c];
      }
    }
  }

  #pragma unroll
  for (int c = 0; c < 64; ++c) vs[w * 65 + c] = acc[c];
  __syncthreads();
  for (int i = 0; i < 64; ++i) {
    int idx = threadIdx.x + i * 128;
    int w2 = idx >> 6, c2 = idx & 63;
    vals_buf[((long)bh * WW + w2) * 64 + c2] = vs[w2 * 65 + c2];
  }
}

// ---------------------------------------------------------------------------
// Kernel 3: 9-neighbor additive attention + concat matmul + LeakyReLU.
// Block = 256 (4 waves), each block: 64 consecutive w at fixed (b,h).
// Wave handles 16 pixels sequentially; lane = channel.
// ---------------------------------------------------------------------------
__global__ __launch_bounds__(256) void attn_kernel(
    const float* __restrict__ q_buf, const float* __restrict__ k_buf,
    const float* __restrict__ enc_t, const float* __restrict__ vals_buf,
    const float* __restrict__ W_agg, const float* __restrict__ b_agg,
    const float* __restrict__ W_attn, const float* __restrict__ b_attn,
    float* __restrict__ out)
{
  __shared__ float cat_s[64][130];
  const int gid = blockIdx.x;
  const int wtile = gid & 1;
  const int bh = gid >> 1;
  const int b = bh >> 7, h = bh & 127;
  const int w0 = wtile * 64;
  const int tid = threadIdx.x;
  const int lane = tid & 63;
  const int wv = tid >> 6;

  const float wagg = W_agg[lane];
  const float bagg = b_agg[0];

  for (int j = 0; j < 16; ++j) {
    const int wl = wv * 16 + j;
    const int w = w0 + wl;
    const long pix = (long)bh * WW + w;

    const float qv = q_buf[pix * 64 + lane];

    float sc[9];
    float m = -1e30f;
    #pragma unroll
    for (int n = 0; n < 9; ++n) {
      const int nh = h + n / 3 - 1;
      const int nw = w + n % 3 - 1;
      const bool valid = (nh >= 0 && nh < HH && nw >= 0 && nw < WW);
      float s;
      if (valid) {
        const long npix = ((long)b * HH + nh) * WW + nw;
        float t = tanhf(qv + k_buf[npix * 64 + lane]) * wagg;
        #pragma unroll
        for (int off = 1; off < 64; off <<= 1) t += __shfl_xor(t, off);
        s = t + bagg;
      } else {
        s = -1e30f;
      }
      sc[n] = s;
      m = fmaxf(m, s);
    }

    float e[9];
    float denom = 0.f;
    #pragma unroll
    for (int n = 0; n < 9; ++n) { e[n] = __expf(sc[n] - m); denom += e[n]; }
    const float inv = 1.f / denom;

    float attn = 0.f;
    #pragma unroll
    for (int n = 0; n < 9; ++n) {
      const int nh = h + n / 3 - 1;
      const int nw = w + n % 3 - 1;
      if (nh >= 0 && nh < HH && nw >= 0 && nw < WW) {
        const long npix = ((long)b * HH + nh) * WW + nw;
        attn += e[n] * inv * enc_t[npix * 64 + lane];
      }
    }

    cat_s[wl][lane]      = vals_buf[pix * 64 + lane];
    cat_s[wl][64 + lane] = attn;
  }
  __syncthreads();

  // out[wl][c] = LeakyReLU(cat[wl] @ W_attn + b_attn), NCHW store
  for (int i = 0; i < 16; ++i) {
    const int c = (tid >> 6) + i * 4;   // uniform within wave -> scalar weights
    const int wl = tid & 63;            // lane -> w (coalesced store)
    float o = b_attn[c];
    for (int d = 0; d < 128; ++d)
      o += cat_s[wl][d] * W_attn[d * 64 + c];
    o = (o >= 0.f) ? o : 0.2f * o;
    out[((long)(b * ENC_C + c) * HH + h) * WW + w0 + wl] = o;
  }
}

// ---------------------------------------------------------------------------
extern "C" void kernel_launch(void* const* d_in, const int* in_sizes, int n_in,
                              void* d_out, int out_size, void* d_ws, size_t ws_size,
                              hipStream_t stream) {
  const float* enc    = (const float*)d_in[0];
  const float* dec    = (const float*)d_in[1];
  const float* W_enc  = (const float*)d_in[2];
  const float* b_enc  = (const float*)d_in[3];
  const float* W_dec  = (const float*)d_in[4];
  const float* b_dec  = (const float*)d_in[5];
  const float* W_agg  = (const float*)d_in[6];
  const float* b_agg  = (const float*)d_in[7];
  const float* W_attn = (const float*)d_in[8];
  const float* b_attn = (const float*)d_in[9];
  const float* conv_w = (const float*)d_in[10];
  const float* conv_b = (const float*)d_in[11];
  float* out = (float*)d_out;

  const long npix = (long)BB * HH * WW;          // 131072
  float* q_buf    = (float*)d_ws;                // [npix][64]
  float* k_buf    = q_buf + npix * 64;           // [npix][64]
  float* enc_t    = k_buf + npix * 64;           // [npix][64]
  float* vals_buf = enc_t + npix * 64;           // [npix][64]
  // total ws use: 4 * 33.5 MB = 134 MB

  hipLaunchKernelGGL(prep_kernel, dim3(BB * HH), dim3(256), 0, stream,
                     enc, dec, W_enc, b_enc, W_dec, b_dec, q_buf, k_buf, enc_t);
  hipLaunchKernelGGL(conv_kernel, dim3(BB * HH), dim3(128), 0, stream,
                     dec, conv_w, conv_b, vals_buf);
  hipLaunchKernelGGL(attn_kernel, dim3(BB * HH * 2), dim3(256), 0, stream,
                     q_buf, k_buf, enc_t, vals_buf, W_agg, b_agg, W_attn, b_attn, out);
}

// Round 2
// 555.694 us; speedup vs baseline: 2.1142x; 2.1142x over previous
//
#include <hip/hip_runtime.h>

#define BB 8
#define ENC_C 64
#define DEC_C 128
#define HH 128
#define WW 128

typedef unsigned short ushort_t;
typedef __attribute__((ext_vector_type(8))) short short8;
typedef __attribute__((ext_vector_type(4))) float f32x4;

static __device__ __forceinline__ ushort_t f2bf(float x) {
  unsigned int u = __builtin_bit_cast(unsigned int, x);
  u += 0x7fff + ((u >> 16) & 1);   // round-to-nearest-even
  return (ushort_t)(u >> 16);
}

// ---------------------------------------------------------------------------
// Kernel 1: per (b,h) row — transpose enc to NHWC, compute k = enc@W_enc+b,
//           q = dec@W_dec+b (both NHWC f32), and emit dec_t (NHWC bf16).
// ---------------------------------------------------------------------------
__global__ __launch_bounds__(256) void prep_kernel(
    const float* __restrict__ enc, const float* __restrict__ dec,
    const float* __restrict__ W_enc, const float* __restrict__ b_enc,
    const float* __restrict__ W_dec, const float* __restrict__ b_dec,
    float* __restrict__ q_buf, float* __restrict__ k_buf,
    float* __restrict__ enc_t, ushort_t* __restrict__ dec_t)
{
  __shared__ float smem[DEC_C * 129];
  const int bh = blockIdx.x;
  const int b = bh >> 7, h = bh & 127;
  const int tid = threadIdx.x;
  const int c = tid & 63;          // lane -> channel
  const int wbase = tid >> 6;      // wave id -> w offset

  // ---- phase 1: encoder tile [64c][128w] ----
  #pragma unroll
  for (int i = 0; i < 32; ++i) {
    int idx = tid + i * 256;
    int cc = idx >> 7, w = idx & 127;
    smem[cc * 129 + w] = enc[((b * ENC_C + cc) * HH + h) * WW + w];
  }
  __syncthreads();

  // write enc_t NHWC
  #pragma unroll
  for (int i = 0; i < 32; ++i) {
    int idx = tid + i * 256;
    int w = idx >> 6, cc = idx & 63;
    enc_t[((long)bh * WW + w) * 64 + cc] = smem[cc * 129 + w];
  }

  // k = enc @ W_enc + b_enc
  {
    float acc[32];
    const float bk = b_enc[c];
    #pragma unroll
    for (int i = 0; i < 32; ++i) acc[i] = bk;
    for (int d = 0; d < 64; ++d) {
      float wgt = W_enc[d * 64 + c];
      #pragma unroll
      for (int i = 0; i < 32; ++i)
        acc[i] += smem[d * 129 + wbase + i * 4] * wgt;
    }
    #pragma unroll
    for (int i = 0; i < 32; ++i)
      k_buf[((long)bh * WW + wbase + i * 4) * 64 + c] = acc[i];
  }
  __syncthreads();

  // ---- phase 2: decoder tile [128d][128w] ----
  #pragma unroll
  for (int i = 0; i < 64; ++i) {
    int idx = tid + i * 256;
    int dd = idx >> 7, w = idx & 127;
    smem[dd * 129 + w] = dec[((b * DEC_C + dd) * HH + h) * WW + w];
  }
  __syncthreads();

  // dec_t NHWC bf16 (for MFMA conv A-operand)
  #pragma unroll
  for (int i = 0; i < 64; ++i) {
    int idx = tid + i * 256;
    int w = idx >> 7, dd = idx & 127;
    dec_t[((long)bh * WW + w) * DEC_C + dd] = f2bf(smem[dd * 129 + w]);
  }

  // q = dec @ W_dec + b_dec
  {
    float acc[32];
    const float bq = b_dec[c];
    #pragma unroll
    for (int i = 0; i < 32; ++i) acc[i] = bq;
    for (int d = 0; d < 128; ++d) {
      float wgt = W_dec[d * 64 + c];
      #pragma unroll
      for (int i = 0; i < 32; ++i)
        acc[i] += smem[d * 129 + wbase + i * 4] * wgt;
    }
    #pragma unroll
    for (int i = 0; i < 32; ++i)
      q_buf[((long)bh * WW + wbase + i * 4) * 64 + c] = acc[i];
  }
}

// ---------------------------------------------------------------------------
// Kernel 1b: pack conv weights into MFMA B-fragment order, bf16.
// packed[((kstep*4 + nf)*64 + lane)*8 + j] = W[k][n],
//   k = tap*128 + dstep*32 + (lane>>4)*8 + j, n = nf*16 + (lane&15),
//   kstep = tap*4 + dstep.  W is conv_w [3][3][128][64] (HWIO).
// ---------------------------------------------------------------------------
__global__ __launch_bounds__(64) void pack_w_kernel(
    const float* __restrict__ conv_w, ushort_t* __restrict__ packed)
{
  const int blk = blockIdx.x;        // kstep*4 + nf, 0..143
  const int l = threadIdx.x;
  const int kstep = blk >> 2, nf = blk & 3;
  const int tap = kstep >> 2, dstep = kstep & 3;
  const int n = nf * 16 + (l & 15);
  const int dbase = dstep * 32 + (l >> 4) * 8;
  ushort_t v[8];
  #pragma unroll
  for (int j = 0; j < 8; ++j)
    v[j] = f2bf(conv_w[(tap * DEC_C + dbase + j) * 64 + n]);
  ushort_t* dst = packed + ((long)blk * 64 + l) * 8;
  #pragma unroll
  for (int j = 0; j < 8; ++j) dst[j] = v[j];
}

// ---------------------------------------------------------------------------
// Kernel 2: 3x3 conv as implicit GEMM via bf16 MFMA.
// Block = 256 (4 waves) per (b,h) row; wave -> 32 pixels x 64 channels.
// K = 9 taps x 128 ch; A-frags from global dec_t (predicated at w borders),
// B-frags from packed weights (coalesced, L2-resident). No LDS.
// ---------------------------------------------------------------------------
__global__ __launch_bounds__(256) void conv_mfma_kernel(
    const ushort_t* __restrict__ dec_t, const ushort_t* __restrict__ packed,
    const float* __restrict__ conv_b, float* __restrict__ vals_buf)
{
  const int bh = blockIdx.x;
  const int b = bh >> 7, h = bh & 127;
  const int tid = threadIdx.x;
  const int l = tid & 63;
  const int wv = tid >> 6;
  const int w0 = wv * 32;
  const int row16 = l & 15, kgrp = l >> 4;

  f32x4 acc[2][4];
  #pragma unroll
  for (int mf = 0; mf < 2; ++mf)
    #pragma unroll
    for (int nf = 0; nf < 4; ++nf)
      acc[mf][nf] = (f32x4){0.f, 0.f, 0.f, 0.f};

  #pragma unroll
  for (int kh = 0; kh < 3; ++kh) {
    const int hh = h + kh - 1;
    if (hh < 0 || hh >= HH) continue;   // block-uniform skip
    const ushort_t* arow = dec_t + ((long)(b * HH + hh) * WW) * DEC_C;
    #pragma unroll
    for (int kw = 0; kw < 3; ++kw) {
      const int tap = kh * 3 + kw;
      #pragma unroll
      for (int ds = 0; ds < 4; ++ds) {
        const int d0 = ds * 32;
        short8 afr[2];
        #pragma unroll
        for (int mf = 0; mf < 2; ++mf) {
          const int wp = w0 + mf * 16 + row16 + kw - 1;
          short8 v = {0, 0, 0, 0, 0, 0, 0, 0};
          if (wp >= 0 && wp < WW)
            v = *(const short8*)(arow + (long)wp * DEC_C + d0 + kgrp * 8);
          afr[mf] = v;
        }
        const int kstep = tap * 4 + ds;
        #pragma unroll
        for (int nf = 0; nf < 4; ++nf) {
          const short8 bfr =
              *(const short8*)(packed + ((long)(kstep * 4 + nf) * 64 + l) * 8);
          acc[0][nf] = __builtin_amdgcn_mfma_f32_16x16x32_bf16(
              afr[0], bfr, acc[0][nf], 0, 0, 0);
          acc[1][nf] = __builtin_amdgcn_mfma_f32_16x16x32_bf16(
              afr[1], bfr, acc[1][nf], 0, 0, 0);
        }
      }
    }
  }

  // epilogue: add bias, store NHWC f32
  #pragma unroll
  for (int mf = 0; mf < 2; ++mf)
    #pragma unroll
    for (int nf = 0; nf < 4; ++nf)
      #pragma unroll
      for (int r = 0; r < 4; ++r) {
        const int w = w0 + mf * 16 + kgrp * 4 + r;
        const int cch = nf * 16 + row16;
        vals_buf[((long)bh * WW + w) * 64 + cch] = acc[mf][nf][r] + conv_b[cch];
      }
}

// ---------------------------------------------------------------------------
// Kernel 3: 9-neighbor additive attention + concat matmul + LeakyReLU.
// ---------------------------------------------------------------------------
__global__ __launch_bounds__(256) void attn_kernel(
    const float* __restrict__ q_buf, const float* __restrict__ k_buf,
    const float* __restrict__ enc_t, const float* __restrict__ vals_buf,
    const float* __restrict__ W_agg, const float* __restrict__ b_agg,
    const float* __restrict__ W_attn, const float* __restrict__ b_attn,
    float* __restrict__ out)
{
  __shared__ float cat_s[64][130];
  const int gid = blockIdx.x;
  const int wtile = gid & 1;
  const int bh = gid >> 1;
  const int b = bh >> 7, h = bh & 127;
  const int w0 = wtile * 64;
  const int tid = threadIdx.x;
  const int lane = tid & 63;
  const int wv = tid >> 6;

  const float wagg = W_agg[lane];
  const float bagg = b_agg[0];

  for (int j = 0; j < 16; ++j) {
    const int wl = wv * 16 + j;
    const int w = w0 + wl;
    const long pix = (long)bh * WW + w;

    const float qv = q_buf[pix * 64 + lane];

    float sc[9];
    float m = -1e30f;
    #pragma unroll
    for (int n = 0; n < 9; ++n) {
      const int nh = h + n / 3 - 1;
      const int nw = w + n % 3 - 1;
      const bool valid = (nh >= 0 && nh < HH && nw >= 0 && nw < WW);
      float s;
      if (valid) {
        const long npix = ((long)b * HH + nh) * WW + nw;
        float t = tanhf(qv + k_buf[npix * 64 + lane]) * wagg;
        #pragma unroll
        for (int off = 1; off < 64; off <<= 1) t += __shfl_xor(t, off);
        s = t + bagg;
      } else {
        s = -1e30f;
      }
      sc[n] = s;
      m = fmaxf(m, s);
    }

    float e[9];
    float denom = 0.f;
    #pragma unroll
    for (int n = 0; n < 9; ++n) { e[n] = __expf(sc[n] - m); denom += e[n]; }
    const float inv = 1.f / denom;

    float attn = 0.f;
    #pragma unroll
    for (int n = 0; n < 9; ++n) {
      const int nh = h + n / 3 - 1;
      const int nw = w + n % 3 - 1;
      if (nh >= 0 && nh < HH && nw >= 0 && nw < WW) {
        const long npix = ((long)b * HH + nh) * WW + nw;
        attn += e[n] * inv * enc_t[npix * 64 + lane];
      }
    }

    cat_s[wl][lane]      = vals_buf[pix * 64 + lane];
    cat_s[wl][64 + lane] = attn;
  }
  __syncthreads();

  // out[wl][c] = LeakyReLU(cat[wl] @ W_attn + b_attn), NCHW store
  for (int i = 0; i < 16; ++i) {
    const int c = (tid >> 6) + i * 4;   // uniform within wave -> scalar weights
    const int wl = tid & 63;            // lane -> w (coalesced store)
    float o = b_attn[c];
    for (int d = 0; d < 128; ++d)
      o += cat_s[wl][d] * W_attn[d * 64 + c];
    o = (o >= 0.f) ? o : 0.2f * o;
    out[((long)(b * ENC_C + c) * HH + h) * WW + w0 + wl] = o;
  }
}

// ---------------------------------------------------------------------------
extern "C" void kernel_launch(void* const* d_in, const int* in_sizes, int n_in,
                              void* d_out, int out_size, void* d_ws, size_t ws_size,
                              hipStream_t stream) {
  const float* enc    = (const float*)d_in[0];
  const float* dec    = (const float*)d_in[1];
  const float* W_enc  = (const float*)d_in[2];
  const float* b_enc  = (const float*)d_in[3];
  const float* W_dec  = (const float*)d_in[4];
  const float* b_dec  = (const float*)d_in[5];
  const float* W_agg  = (const float*)d_in[6];
  const float* b_agg  = (const float*)d_in[7];
  const float* W_attn = (const float*)d_in[8];
  const float* b_attn = (const float*)d_in[9];
  const float* conv_w = (const float*)d_in[10];
  const float* conv_b = (const float*)d_in[11];
  float* out = (float*)d_out;

  const long npix = (long)BB * HH * WW;            // 131072
  float* q_buf      = (float*)d_ws;                // [npix][64]
  float* k_buf      = q_buf + npix * 64;           // [npix][64]
  float* enc_t      = k_buf + npix * 64;           // [npix][64]
  float* vals_buf   = enc_t + npix * 64;           // [npix][64]
  ushort_t* dec_t   = (ushort_t*)(vals_buf + npix * 64); // [npix][128] bf16
  ushort_t* packed  = dec_t + npix * 128;          // [1152][64] bf16 frag-ordered
  // total ws use: 134 MB + 33.6 MB + 0.15 MB ~= 168 MB

  hipLaunchKernelGGL(prep_kernel, dim3(BB * HH), dim3(256), 0, stream,
                     enc, dec, W_enc, b_enc, W_dec, b_dec, q_buf, k_buf, enc_t, dec_t);
  hipLaunchKernelGGL(pack_w_kernel, dim3(144), dim3(64), 0, stream,
                     conv_w, packed);
  hipLaunchKernelGGL(conv_mfma_kernel, dim3(BB * HH), dim3(256), 0, stream,
                     dec_t, packed, conv_b, vals_buf);
  hipLaunchKernelGGL(attn_kernel, dim3(BB * HH * 2), dim3(256), 0, stream,
                     q_buf, k_buf, enc_t, vals_buf, W_agg, b_agg, W_attn, b_attn, out);
}

// Round 3
// 310.392 us; speedup vs baseline: 3.7850x; 1.7903x over previous
//
#include <hip/hip_runtime.h>

#define BB 8
#define ENC_C 64
#define DEC_C 128
#define HH 128
#define WW 128

typedef unsigned short ushort_t;
typedef __attribute__((ext_vector_type(8))) short short8;
typedef __attribute__((ext_vector_type(4))) float f32x4;

static __device__ __forceinline__ ushort_t f2bf(float x) {
  unsigned int u = __builtin_bit_cast(unsigned int, x);
  u += 0x7fff + ((u >> 16) & 1);   // round-to-nearest-even
  return (ushort_t)(u >> 16);
}

// ---------------------------------------------------------------------------
// Kernel 1: per (b,h) row — k = enc@W_enc+b (CHW f32), q = dec@W_dec+b (CHW
// f32), dec_t (NHWC bf16). lane=w, 2 channel-halves of 32 accumulators.
// ---------------------------------------------------------------------------
__global__ __launch_bounds__(256) void prep_kernel(
    const float* __restrict__ enc, const float* __restrict__ dec,
    const float* __restrict__ W_enc, const float* __restrict__ b_enc,
    const float* __restrict__ W_dec, const float* __restrict__ b_dec,
    float* __restrict__ q_chw, float* __restrict__ k_chw,
    ushort_t* __restrict__ dec_t)
{
  __shared__ float smem[DEC_C * 129];
  const int bh = blockIdx.x;
  const int b = bh >> 7, h = bh & 127;
  const int tid = threadIdx.x;
  const int w = tid & 127;
  const int ch = tid >> 7;           // 0/1: channel half (wave-uniform)

  // ---- encoder tile [64c][128w] ----
  #pragma unroll
  for (int i = 0; i < 32; ++i) {
    int idx = tid + i * 256;
    int cc = idx >> 7, wl = idx & 127;
    smem[cc * 129 + wl] = enc[((b * ENC_C + cc) * HH + h) * WW + wl];
  }
  __syncthreads();

  // k = enc @ W_enc + b_enc  (CHW store, coalesced across lane=w)
  {
    float acc[32];
    #pragma unroll
    for (int i = 0; i < 32; ++i) acc[i] = b_enc[ch * 32 + i];
    for (int d = 0; d < 64; ++d) {
      float x = smem[d * 129 + w];
      #pragma unroll
      for (int i = 0; i < 32; ++i)
        acc[i] += x * W_enc[d * 64 + ch * 32 + i];   // wave-uniform -> s_load
    }
    #pragma unroll
    for (int i = 0; i < 32; ++i)
      k_chw[((long)(b * ENC_C + ch * 32 + i) * HH + h) * WW + w] = acc[i];
  }
  __syncthreads();

  // ---- decoder tile [128d][128w] ----
  #pragma unroll
  for (int i = 0; i < 64; ++i) {
    int idx = tid + i * 256;
    int dd = idx >> 7, wl = idx & 127;
    smem[dd * 129 + wl] = dec[((b * DEC_C + dd) * HH + h) * WW + wl];
  }
  __syncthreads();

  // dec_t NHWC bf16 (MFMA conv A-operand)
  #pragma unroll
  for (int i = 0; i < 64; ++i) {
    int idx = tid + i * 256;
    int wl = idx >> 7, dd = idx & 127;
    dec_t[((long)bh * WW + wl) * DEC_C + dd] = f2bf(smem[dd * 129 + wl]);
  }

  // q = dec @ W_dec + b_dec  (CHW store)
  {
    float acc[32];
    #pragma unroll
    for (int i = 0; i < 32; ++i) acc[i] = b_dec[ch * 32 + i];
    for (int d = 0; d < 128; ++d) {
      float x = smem[d * 129 + w];
      #pragma unroll
      for (int i = 0; i < 32; ++i)
        acc[i] += x * W_dec[d * 64 + ch * 32 + i];
    }
    #pragma unroll
    for (int i = 0; i < 32; ++i)
      q_chw[((long)(b * ENC_C + ch * 32 + i) * HH + h) * WW + w] = acc[i];
  }
}

// ---------------------------------------------------------------------------
// Kernel 1b: pack conv weights (blk<144) and W_attn (blk>=144) into MFMA
// B-fragment order, bf16. B-frag: lane l holds B[k=(l>>4)*8+j][n=nf*16+(l&15)].
// ---------------------------------------------------------------------------
__global__ __launch_bounds__(64) void pack_w_kernel(
    const float* __restrict__ conv_w, const float* __restrict__ W_attn,
    ushort_t* __restrict__ packedC, ushort_t* __restrict__ packedA)
{
  const int blk = blockIdx.x;
  const int l = threadIdx.x;
  if (blk < 144) {
    const int kstep = blk >> 2, nf = blk & 3;
    const int tap = kstep >> 2, dstep = kstep & 3;
    const int n = nf * 16 + (l & 15);
    const int dbase = dstep * 32 + (l >> 4) * 8;
    ushort_t v[8];
    #pragma unroll
    for (int j = 0; j < 8; ++j)
      v[j] = f2bf(conv_w[(tap * DEC_C + dbase + j) * 64 + n]);
    ushort_t* dst = packedC + ((long)blk * 64 + l) * 8;
    #pragma unroll
    for (int j = 0; j < 8; ++j) dst[j] = v[j];
  } else {
    const int bb = blk - 144;            // 0..15
    const int ks = bb >> 2, nf = bb & 3;
    const int n = nf * 16 + (l & 15);
    const int kbase = ks * 32 + (l >> 4) * 8;
    ushort_t v[8];
    #pragma unroll
    for (int j = 0; j < 8; ++j)
      v[j] = f2bf(W_attn[(kbase + j) * 64 + n]);
    ushort_t* dst = packedA + ((long)bb * 64 + l) * 8;
    #pragma unroll
    for (int j = 0; j < 8; ++j) dst[j] = v[j];
  }
}

// ---------------------------------------------------------------------------
// Kernel 2: 3x3 conv as implicit GEMM via bf16 MFMA -> vals NHWC bf16.
// ---------------------------------------------------------------------------
__global__ __launch_bounds__(256) void conv_mfma_kernel(
    const ushort_t* __restrict__ dec_t, const ushort_t* __restrict__ packed,
    const float* __restrict__ conv_b, ushort_t* __restrict__ vals_nhwc)
{
  const int bh = blockIdx.x;
  const int b = bh >> 7, h = bh & 127;
  const int tid = threadIdx.x;
  const int l = tid & 63;
  const int wv = tid >> 6;
  const int w0 = wv * 32;
  const int row16 = l & 15, kgrp = l >> 4;

  f32x4 acc[2][4];
  #pragma unroll
  for (int mf = 0; mf < 2; ++mf)
    #pragma unroll
    for (int nf = 0; nf < 4; ++nf)
      acc[mf][nf] = (f32x4){0.f, 0.f, 0.f, 0.f};

  #pragma unroll
  for (int kh = 0; kh < 3; ++kh) {
    const int hh = h + kh - 1;
    if (hh < 0 || hh >= HH) continue;   // block-uniform skip
    const ushort_t* arow = dec_t + ((long)(b * HH + hh) * WW) * DEC_C;
    #pragma unroll
    for (int kw = 0; kw < 3; ++kw) {
      const int tap = kh * 3 + kw;
      #pragma unroll
      for (int ds = 0; ds < 4; ++ds) {
        const int d0 = ds * 32;
        short8 afr[2];
        #pragma unroll
        for (int mf = 0; mf < 2; ++mf) {
          const int wp = w0 + mf * 16 + row16 + kw - 1;
          short8 v = {0, 0, 0, 0, 0, 0, 0, 0};
          if (wp >= 0 && wp < WW)
            v = *(const short8*)(arow + (long)wp * DEC_C + d0 + kgrp * 8);
          afr[mf] = v;
        }
        const int kstep = tap * 4 + ds;
        #pragma unroll
        for (int nf = 0; nf < 4; ++nf) {
          const short8 bfr =
              *(const short8*)(packed + ((long)(kstep * 4 + nf) * 64 + l) * 8);
          acc[0][nf] = __builtin_amdgcn_mfma_f32_16x16x32_bf16(
              afr[0], bfr, acc[0][nf], 0, 0, 0);
          acc[1][nf] = __builtin_amdgcn_mfma_f32_16x16x32_bf16(
              afr[1], bfr, acc[1][nf], 0, 0, 0);
        }
      }
    }
  }

  #pragma unroll
  for (int mf = 0; mf < 2; ++mf)
    #pragma unroll
    for (int nf = 0; nf < 4; ++nf)
      #pragma unroll
      for (int r = 0; r < 4; ++r) {
        const int w = w0 + mf * 16 + kgrp * 4 + r;
        const int cch = nf * 16 + row16;
        vals_nhwc[((long)bh * WW + w) * 64 + cch] = f2bf(acc[mf][nf][r] + conv_b[cch]);
      }
}

// ---------------------------------------------------------------------------
// Kernel 3: attention, lane = pixel. q/k CHW f32, enc NCHW (input layout).
// Serial channel loop = in-register reduction; no shuffles, no redundant
// softmax. Fast tanh via exp2+rcp. Output attn_vec NHWC bf16 via LDS xpose.
// ---------------------------------------------------------------------------
__global__ __launch_bounds__(256) void attn_kernel(
    const float* __restrict__ q_chw, const float* __restrict__ k_chw,
    const float* __restrict__ enc, const float* __restrict__ W_agg,
    const float* __restrict__ b_agg, ushort_t* __restrict__ attn_nhwc)
{
  __shared__ ushort_t att_lds[2][64][130];
  const int half = threadIdx.x >> 7;
  const int w = threadIdx.x & 127;
  const int bh = blockIdx.x * 2 + half;
  const int b = bh >> 7, h = bh & 127;

  int off[9]; float s[9]; bool valid[9];
  #pragma unroll
  for (int n = 0; n < 9; ++n) {
    const int dh = n / 3 - 1, dw = n % 3 - 1;
    const int nh = h + dh, nw = w + dw;
    valid[n] = (nh >= 0 && nh < HH && nw >= 0 && nw < WW);
    const int nhc = min(max(nh, 0), HH - 1);
    const int nwc = min(max(nw, 0), WW - 1);
    off[n] = nhc * WW + nwc;           // clamped: loads always in-bounds
    s[n] = 0.f;
  }

  const long plane = (long)HH * WW;
  const float* qp = q_chw + ((long)(b * ENC_C) * HH + h) * WW + w;
  const float* kp = k_chw + (long)(b * ENC_C) * plane;
  const float* ep = enc   + (long)(b * ENC_C) * plane;
  const float bagg = b_agg[0];

  // pass 1: scores
  for (int c = 0; c < 64; ++c) {
    const float qv = qp[(long)c * plane];
    const float wac = W_agg[c];                  // wave-uniform -> s_load
    const float* kc = kp + (long)c * plane;
    #pragma unroll
    for (int n = 0; n < 9; ++n) {
      float x = qv + kc[off[n]];
      x = fminf(fmaxf(x, -15.f), 15.f);
      float z = __builtin_amdgcn_exp2f(x * 2.88539008f);  // e^(2x)
      float t = __builtin_fmaf(-2.f, __builtin_amdgcn_rcpf(z + 1.f), 1.f);
      s[n] += t * wac;
    }
  }

  // softmax over valid neighbors
  float m = -1e30f;
  #pragma unroll
  for (int n = 0; n < 9; ++n) {
    s[n] = valid[n] ? (s[n] + bagg) : -1e30f;
    m = fmaxf(m, s[n]);
  }
  float attw[9]; float denom = 0.f;
  #pragma unroll
  for (int n = 0; n < 9; ++n) {
    attw[n] = __builtin_amdgcn_exp2f((s[n] - m) * 1.44269504f);
    denom += attw[n];
  }
  const float inv = __builtin_amdgcn_rcpf(denom);
  #pragma unroll
  for (int n = 0; n < 9; ++n) attw[n] *= inv;   // invalid -> exactly 0

  // pass 2: weighted encoder-neighbor sum, per channel
  for (int c = 0; c < 64; ++c) {
    const float* ec = ep + (long)c * plane;
    float a = 0.f;
    #pragma unroll
    for (int n = 0; n < 9; ++n) a += attw[n] * ec[off[n]];
    att_lds[half][c][w] = f2bf(a);
  }
  __syncthreads();

  // transposed NHWC bf16 store (coalesced)
  const int c2 = w & 63;
  const int sub = w >> 6;
  #pragma unroll
  for (int i = 0; i < 64; ++i) {
    const int wp = i * 2 + sub;
    attn_nhwc[((long)bh * WW + wp) * 64 + c2] = att_lds[half][c2][wp];
  }
}

// ---------------------------------------------------------------------------
// Kernel 4: out = LeakyReLU([vals; attn] @ W_attn + b) via MFMA, NCHW store.
// ---------------------------------------------------------------------------
__global__ __launch_bounds__(256) void out_kernel(
    const ushort_t* __restrict__ vals_nhwc, const ushort_t* __restrict__ attn_nhwc,
    const ushort_t* __restrict__ packedA, const float* __restrict__ b_attn,
    float* __restrict__ out)
{
  __shared__ float out_lds[128 * 65];
  const int bh = blockIdx.x;
  const int b = bh >> 7, h = bh & 127;
  const int tid = threadIdx.x;
  const int l = tid & 63;
  const int wv = tid >> 6;
  const int w0 = wv * 32;
  const int row16 = l & 15, kg = l >> 4;

  f32x4 acc[2][4];
  #pragma unroll
  for (int mf = 0; mf < 2; ++mf)
    #pragma unroll
    for (int nf = 0; nf < 4; ++nf)
      acc[mf][nf] = (f32x4){0.f, 0.f, 0.f, 0.f};

  #pragma unroll
  for (int ks = 0; ks < 4; ++ks) {
    const ushort_t* src = (ks < 2)
        ? vals_nhwc + ((long)bh * WW) * 64 + ks * 32
        : attn_nhwc + ((long)bh * WW) * 64 + (ks - 2) * 32;
    short8 afr[2];
    #pragma unroll
    for (int mf = 0; mf < 2; ++mf) {
      const int pix = w0 + mf * 16 + row16;
      afr[mf] = *(const short8*)(src + (long)pix * 64 + kg * 8);
    }
    #pragma unroll
    for (int nf = 0; nf < 4; ++nf) {
      const short8 bfr =
          *(const short8*)(packedA + ((long)(ks * 4 + nf) * 64 + l) * 8);
      acc[0][nf] = __builtin_amdgcn_mfma_f32_16x16x32_bf16(
          afr[0], bfr, acc[0][nf], 0, 0, 0);
      acc[1][nf] = __builtin_amdgcn_mfma_f32_16x16x32_bf16(
          afr[1], bfr, acc[1][nf], 0, 0, 0);
    }
  }

  #pragma unroll
  for (int mf = 0; mf < 2; ++mf)
    #pragma unroll
    for (int nf = 0; nf < 4; ++nf)
      #pragma unroll
      for (int r = 0; r < 4; ++r) {
        const int pix = w0 + mf * 16 + kg * 4 + r;
        const int cch = nf * 16 + row16;
        float o = acc[mf][nf][r] + b_attn[cch];
        o = (o >= 0.f) ? o : 0.2f * o;
        out_lds[pix * 65 + cch] = o;
      }
  __syncthreads();

  #pragma unroll
  for (int i = 0; i < 32; ++i) {
    const int idx = tid + i * 256;
    const int cch = idx >> 7, wp = idx & 127;
    out[((long)(b * ENC_C + cch) * HH + h) * WW + wp] = out_lds[wp * 65 + cch];
  }
}

// ---------------------------------------------------------------------------
extern "C" void kernel_launch(void* const* d_in, const int* in_sizes, int n_in,
                              void* d_out, int out_size, void* d_ws, size_t ws_size,
                              hipStream_t stream) {
  const float* enc    = (const float*)d_in[0];
  const float* dec    = (const float*)d_in[1];
  const float* W_enc  = (const float*)d_in[2];
  const float* b_enc  = (const float*)d_in[3];
  const float* W_dec  = (const float*)d_in[4];
  const float* b_dec  = (const float*)d_in[5];
  const float* W_agg  = (const float*)d_in[6];
  const float* b_agg  = (const float*)d_in[7];
  const float* W_attn = (const float*)d_in[8];
  const float* b_attn = (const float*)d_in[9];
  const float* conv_w = (const float*)d_in[10];
  const float* conv_b = (const float*)d_in[11];
  float* out = (float*)d_out;

  const long npix = (long)BB * HH * WW;               // 131072
  float* q_chw      = (float*)d_ws;                   // [B][64][H][W] f32
  float* k_chw      = q_chw + npix * 64;              // [B][64][H][W] f32
  ushort_t* dec_t   = (ushort_t*)(k_chw + npix * 64); // [npix][128] bf16
  ushort_t* vals    = dec_t + npix * 128;             // [npix][64] bf16
  ushort_t* attn    = vals + npix * 64;               // [npix][64] bf16
  ushort_t* packedC = attn + npix * 64;               // conv W frags
  ushort_t* packedA = packedC + 1152 * 64;            // attn W frags

  hipLaunchKernelGGL(prep_kernel, dim3(BB * HH), dim3(256), 0, stream,
                     enc, dec, W_enc, b_enc, W_dec, b_dec, q_chw, k_chw, dec_t);
  hipLaunchKernelGGL(pack_w_kernel, dim3(160), dim3(64), 0, stream,
                     conv_w, W_attn, packedC, packedA);
  hipLaunchKernelGGL(conv_mfma_kernel, dim3(BB * HH), dim3(256), 0, stream,
                     dec_t, packedC, conv_b, vals);
  hipLaunchKernelGGL(attn_kernel, dim3(BB * HH / 2), dim3(256), 0, stream,
                     q_chw, k_chw, enc, W_agg, b_agg, attn);
  hipLaunchKernelGGL(out_kernel, dim3(BB * HH), dim3(256), 0, stream,
                     vals, attn, packedA, b_attn, out);
}

// Round 4
// 175.872 us; speedup vs baseline: 6.6800x; 1.7649x over previous
//
#include <hip/hip_runtime.h>

#define BB 8
#define ENC_C 64
#define DEC_C 128
#define HH 128
#define WW 128

typedef unsigned short ushort_t;
typedef __attribute__((ext_vector_type(8))) short short8;
typedef __attribute__((ext_vector_type(4))) float f32x4;

static __device__ __forceinline__ ushort_t f2bf(float x) {
  unsigned int u = __builtin_bit_cast(unsigned int, x);
  u += 0x7fff + ((u >> 16) & 1);   // round-to-nearest-even
  return (ushort_t)(u >> 16);
}

// ---------------------------------------------------------------------------
// Kernel 0: pack B-fragments (bf16) for all four matmuls.
//   blk 0..143   : conv_w   (K=1152 over taps)       -> packedC
//   blk 144..159 : W_attn   (K=128)                   -> packedA
//   blk 160..175 : W_dec    (K=128)                   -> packedQ
//   blk 176..183 : W_enc    (K=64)                    -> packedK
// Frag: lane l, elem j holds B[k = ks*32 + (l>>4)*8 + j][n = nf*16 + (l&15)].
// ---------------------------------------------------------------------------
__global__ __launch_bounds__(64) void pack_w_kernel(
    const float* __restrict__ conv_w, const float* __restrict__ W_attn,
    const float* __restrict__ W_dec, const float* __restrict__ W_enc,
    ushort_t* __restrict__ packedC, ushort_t* __restrict__ packedA,
    ushort_t* __restrict__ packedQ, ushort_t* __restrict__ packedK)
{
  const int blk = blockIdx.x;
  const int l = threadIdx.x;
  const float* W;
  ushort_t* dst;
  int bb;
  if (blk < 144) {
    const int kstep = blk >> 2, nf = blk & 3;
    const int tap = kstep >> 2, dstep = kstep & 3;
    const int n = nf * 16 + (l & 15);
    const int dbase = dstep * 32 + (l >> 4) * 8;
    ushort_t v[8];
    #pragma unroll
    for (int j = 0; j < 8; ++j)
      v[j] = f2bf(conv_w[(tap * DEC_C + dbase + j) * 64 + n]);
    ushort_t* d = packedC + ((long)blk * 64 + l) * 8;
    #pragma unroll
    for (int j = 0; j < 8; ++j) d[j] = v[j];
    return;
  } else if (blk < 160) {
    W = W_attn; dst = packedA; bb = blk - 144;
  } else if (blk < 176) {
    W = W_dec;  dst = packedQ; bb = blk - 160;
  } else {
    W = W_enc;  dst = packedK; bb = blk - 176;
  }
  const int ks = bb >> 2, nf = bb & 3;
  const int n = nf * 16 + (l & 15);
  const int kbase = ks * 32 + (l >> 4) * 8;
  ushort_t v[8];
  #pragma unroll
  for (int j = 0; j < 8; ++j)
    v[j] = f2bf(W[(kbase + j) * 64 + n]);
  ushort_t* d = dst + ((long)bb * 64 + l) * 8;
  #pragma unroll
  for (int j = 0; j < 8; ++j) d[j] = v[j];
}

// ---------------------------------------------------------------------------
// Kernel 1: per (b,h) row — MFMA q = dec@W_dec, k = enc@W_enc; outputs
// q_chw/k_chw (CHW f32, bias added) and dec_t (NHWC bf16).
// LDS: one 64ch x 128w f32 tile (33 KB) reused; dec in 2 channel-halves.
// ---------------------------------------------------------------------------
__global__ __launch_bounds__(256) void prep_kernel(
    const float* __restrict__ enc, const float* __restrict__ dec,
    const ushort_t* __restrict__ packedQ, const ushort_t* __restrict__ packedK,
    const float* __restrict__ b_enc, const float* __restrict__ b_dec,
    float* __restrict__ q_chw, float* __restrict__ k_chw,
    ushort_t* __restrict__ dec_t)
{
  __shared__ float smem[64 * 129];
  const int bh = blockIdx.x;
  const int b = bh >> 7, h = bh & 127;
  const int tid = threadIdx.x;
  const int l = tid & 63;
  const int wv = tid >> 6;
  const int w0 = wv * 32;
  const int row16 = l & 15, kg = l >> 4;

  f32x4 accq[2][4], acck[2][4];
  #pragma unroll
  for (int mf = 0; mf < 2; ++mf)
    #pragma unroll
    for (int nf = 0; nf < 4; ++nf) {
      accq[mf][nf] = (f32x4){0.f, 0.f, 0.f, 0.f};
      acck[mf][nf] = (f32x4){0.f, 0.f, 0.f, 0.f};
    }

  // ---- encoder tile [64c][128w] -> k MFMA ----
  #pragma unroll
  for (int i = 0; i < 32; ++i) {
    int idx = tid + i * 256;
    int cc = idx >> 7, wl = idx & 127;
    smem[cc * 129 + wl] = enc[((b * ENC_C + cc) * HH + h) * WW + wl];
  }
  __syncthreads();

  #pragma unroll
  for (int ks = 0; ks < 2; ++ks) {
    short8 afr[2];
    #pragma unroll
    for (int mf = 0; mf < 2; ++mf) {
      const int p = w0 + mf * 16 + row16;
      short8 a;
      #pragma unroll
      for (int j = 0; j < 8; ++j)
        a[j] = (short)f2bf(smem[(ks * 32 + kg * 8 + j) * 129 + p]);
      afr[mf] = a;
    }
    #pragma unroll
    for (int nf = 0; nf < 4; ++nf) {
      const short8 bfr =
          *(const short8*)(packedK + ((long)(ks * 4 + nf) * 64 + l) * 8);
      acck[0][nf] = __builtin_amdgcn_mfma_f32_16x16x32_bf16(
          afr[0], bfr, acck[0][nf], 0, 0, 0);
      acck[1][nf] = __builtin_amdgcn_mfma_f32_16x16x32_bf16(
          afr[1], bfr, acck[1][nf], 0, 0, 0);
    }
  }
  __syncthreads();

  // ---- decoder tile in two 64-channel halves -> dec_t + q MFMA ----
  #pragma unroll
  for (int hf = 0; hf < 2; ++hf) {
    #pragma unroll
    for (int i = 0; i < 32; ++i) {
      int idx = tid + i * 256;
      int cc = idx >> 7, wl = idx & 127;
      smem[cc * 129 + wl] = dec[((b * DEC_C + hf * 64 + cc) * HH + h) * WW + wl];
    }
    __syncthreads();

    // dec_t NHWC bf16 (conv A-operand)
    #pragma unroll
    for (int i = 0; i < 32; ++i) {
      int idx = tid + i * 256;
      int wl = idx >> 6, cc = idx & 63;
      dec_t[((long)bh * WW + wl) * DEC_C + hf * 64 + cc] =
          f2bf(smem[cc * 129 + wl]);
    }

    #pragma unroll
    for (int ks2 = 0; ks2 < 2; ++ks2) {
      const int ks = hf * 2 + ks2;
      short8 afr[2];
      #pragma unroll
      for (int mf = 0; mf < 2; ++mf) {
        const int p = w0 + mf * 16 + row16;
        short8 a;
        #pragma unroll
        for (int j = 0; j < 8; ++j)
          a[j] = (short)f2bf(smem[(ks2 * 32 + kg * 8 + j) * 129 + p]);
        afr[mf] = a;
      }
      #pragma unroll
      for (int nf = 0; nf < 4; ++nf) {
        const short8 bfr =
            *(const short8*)(packedQ + ((long)(ks * 4 + nf) * 64 + l) * 8);
        accq[0][nf] = __builtin_amdgcn_mfma_f32_16x16x32_bf16(
            afr[0], bfr, accq[0][nf], 0, 0, 0);
        accq[1][nf] = __builtin_amdgcn_mfma_f32_16x16x32_bf16(
            afr[1], bfr, accq[1][nf], 0, 0, 0);
      }
    }
    __syncthreads();
  }

  // ---- epilogue: LDS-transpose accumulators to CHW f32 (+bias) ----
  // q
  #pragma unroll
  for (int mf = 0; mf < 2; ++mf)
    #pragma unroll
    for (int nf = 0; nf < 4; ++nf)
      #pragma unroll
      for (int r = 0; r < 4; ++r)
        smem[(nf * 16 + row16) * 129 + w0 + mf * 16 + kg * 4 + r] =
            accq[mf][nf][r];
  __syncthreads();
  #pragma unroll
  for (int i = 0; i < 32; ++i) {
    int idx = tid + i * 256;
    int c = idx >> 7, wl = idx & 127;
    q_chw[((long)(b * ENC_C + c) * HH + h) * WW + wl] =
        smem[c * 129 + wl] + b_dec[c];
  }
  __syncthreads();
  // k
  #pragma unroll
  for (int mf = 0; mf < 2; ++mf)
    #pragma unroll
    for (int nf = 0; nf < 4; ++nf)
      #pragma unroll
      for (int r = 0; r < 4; ++r)
        smem[(nf * 16 + row16) * 129 + w0 + mf * 16 + kg * 4 + r] =
            acck[mf][nf][r];
  __syncthreads();
  #pragma unroll
  for (int i = 0; i < 32; ++i) {
    int idx = tid + i * 256;
    int c = idx >> 7, wl = idx & 127;
    k_chw[((long)(b * ENC_C + c) * HH + h) * WW + wl] =
        smem[c * 129 + wl] + b_enc[c];
  }
}

// ---------------------------------------------------------------------------
// Kernel 2: 3x3 conv as implicit GEMM via bf16 MFMA -> vals NHWC bf16.
// ---------------------------------------------------------------------------
__global__ __launch_bounds__(256) void conv_mfma_kernel(
    const ushort_t* __restrict__ dec_t, const ushort_t* __restrict__ packed,
    const float* __restrict__ conv_b, ushort_t* __restrict__ vals_nhwc)
{
  const int bh = blockIdx.x;
  const int b = bh >> 7, h = bh & 127;
  const int tid = threadIdx.x;
  const int l = tid & 63;
  const int wv = tid >> 6;
  const int w0 = wv * 32;
  const int row16 = l & 15, kgrp = l >> 4;

  f32x4 acc[2][4];
  #pragma unroll
  for (int mf = 0; mf < 2; ++mf)
    #pragma unroll
    for (int nf = 0; nf < 4; ++nf)
      acc[mf][nf] = (f32x4){0.f, 0.f, 0.f, 0.f};

  #pragma unroll
  for (int kh = 0; kh < 3; ++kh) {
    const int hh = h + kh - 1;
    if (hh < 0 || hh >= HH) continue;   // block-uniform skip
    const ushort_t* arow = dec_t + ((long)(b * HH + hh) * WW) * DEC_C;
    #pragma unroll
    for (int kw = 0; kw < 3; ++kw) {
      const int tap = kh * 3 + kw;
      #pragma unroll
      for (int ds = 0; ds < 4; ++ds) {
        const int d0 = ds * 32;
        short8 afr[2];
        #pragma unroll
        for (int mf = 0; mf < 2; ++mf) {
          const int wp = w0 + mf * 16 + row16 + kw - 1;
          short8 v = {0, 0, 0, 0, 0, 0, 0, 0};
          if (wp >= 0 && wp < WW)
            v = *(const short8*)(arow + (long)wp * DEC_C + d0 + kgrp * 8);
          afr[mf] = v;
        }
        const int kstep = tap * 4 + ds;
        #pragma unroll
        for (int nf = 0; nf < 4; ++nf) {
          const short8 bfr =
              *(const short8*)(packed + ((long)(kstep * 4 + nf) * 64 + l) * 8);
          acc[0][nf] = __builtin_amdgcn_mfma_f32_16x16x32_bf16(
              afr[0], bfr, acc[0][nf], 0, 0, 0);
          acc[1][nf] = __builtin_amdgcn_mfma_f32_16x16x32_bf16(
              afr[1], bfr, acc[1][nf], 0, 0, 0);
        }
      }
    }
  }

  #pragma unroll
  for (int mf = 0; mf < 2; ++mf)
    #pragma unroll
    for (int nf = 0; nf < 4; ++nf)
      #pragma unroll
      for (int r = 0; r < 4; ++r) {
        const int w = w0 + mf * 16 + kgrp * 4 + r;
        const int cch = nf * 16 + row16;
        vals_nhwc[((long)bh * WW + w) * 64 + cch] = f2bf(acc[mf][nf][r] + conv_b[cch]);
      }
}

// ---------------------------------------------------------------------------
// Kernel 3: attention, lane = pixel. q/k CHW f32, enc NCHW (input layout).
// ---------------------------------------------------------------------------
__global__ __launch_bounds__(256) void attn_kernel(
    const float* __restrict__ q_chw, const float* __restrict__ k_chw,
    const float* __restrict__ enc, const float* __restrict__ W_agg,
    const float* __restrict__ b_agg, ushort_t* __restrict__ attn_nhwc)
{
  __shared__ ushort_t att_lds[2][64][130];
  const int half = threadIdx.x >> 7;
  const int w = threadIdx.x & 127;
  const int bh = blockIdx.x * 2 + half;
  const int b = bh >> 7, h = bh & 127;

  int off[9]; float s[9]; bool valid[9];
  #pragma unroll
  for (int n = 0; n < 9; ++n) {
    const int dh = n / 3 - 1, dw = n % 3 - 1;
    const int nh = h + dh, nw = w + dw;
    valid[n] = (nh >= 0 && nh < HH && nw >= 0 && nw < WW);
    const int nhc = min(max(nh, 0), HH - 1);
    const int nwc = min(max(nw, 0), WW - 1);
    off[n] = nhc * WW + nwc;           // clamped: loads always in-bounds
    s[n] = 0.f;
  }

  const long plane = (long)HH * WW;
  const float* qp = q_chw + ((long)(b * ENC_C) * HH + h) * WW + w;
  const float* kp = k_chw + (long)(b * ENC_C) * plane;
  const float* ep = enc   + (long)(b * ENC_C) * plane;
  const float bagg = b_agg[0];

  // pass 1: scores
  for (int c = 0; c < 64; ++c) {
    const float qv = qp[(long)c * plane];
    const float wac = W_agg[c];                  // wave-uniform -> s_load
    const float* kc = kp + (long)c * plane;
    #pragma unroll
    for (int n = 0; n < 9; ++n) {
      float x = qv + kc[off[n]];
      x = fminf(fmaxf(x, -15.f), 15.f);
      float z = __builtin_amdgcn_exp2f(x * 2.88539008f);  // e^(2x)
      float t = __builtin_fmaf(-2.f, __builtin_amdgcn_rcpf(z + 1.f), 1.f);
      s[n] += t * wac;
    }
  }

  // softmax over valid neighbors
  float m = -1e30f;
  #pragma unroll
  for (int n = 0; n < 9; ++n) {
    s[n] = valid[n] ? (s[n] + bagg) : -1e30f;
    m = fmaxf(m, s[n]);
  }
  float attw[9]; float denom = 0.f;
  #pragma unroll
  for (int n = 0; n < 9; ++n) {
    attw[n] = __builtin_amdgcn_exp2f((s[n] - m) * 1.44269504f);
    denom += attw[n];
  }
  const float inv = __builtin_amdgcn_rcpf(denom);
  #pragma unroll
  for (int n = 0; n < 9; ++n) attw[n] *= inv;   // invalid -> exactly 0

  // pass 2: weighted encoder-neighbor sum, per channel
  for (int c = 0; c < 64; ++c) {
    const float* ec = ep + (long)c * plane;
    float a = 0.f;
    #pragma unroll
    for (int n = 0; n < 9; ++n) a += attw[n] * ec[off[n]];
    att_lds[half][c][w] = f2bf(a);
  }
  __syncthreads();

  // transposed NHWC bf16 store (coalesced)
  const int c2 = w & 63;
  const int sub = w >> 6;
  #pragma unroll
  for (int i = 0; i < 64; ++i) {
    const int wp = i * 2 + sub;
    attn_nhwc[((long)bh * WW + wp) * 64 + c2] = att_lds[half][c2][wp];
  }
}

// ---------------------------------------------------------------------------
// Kernel 4: out = LeakyReLU([vals; attn] @ W_attn + b) via MFMA, NCHW store.
// ---------------------------------------------------------------------------
__global__ __launch_bounds__(256) void out_kernel(
    const ushort_t* __restrict__ vals_nhwc, const ushort_t* __restrict__ attn_nhwc,
    const ushort_t* __restrict__ packedA, const float* __restrict__ b_attn,
    float* __restrict__ out)
{
  __shared__ float out_lds[128 * 65];
  const int bh = blockIdx.x;
  const int b = bh >> 7, h = bh & 127;
  const int tid = threadIdx.x;
  const int l = tid & 63;
  const int wv = tid >> 6;
  const int w0 = wv * 32;
  const int row16 = l & 15, kg = l >> 4;

  f32x4 acc[2][4];
  #pragma unroll
  for (int mf = 0; mf < 2; ++mf)
    #pragma unroll
    for (int nf = 0; nf < 4; ++nf)
      acc[mf][nf] = (f32x4){0.f, 0.f, 0.f, 0.f};

  #pragma unroll
  for (int ks = 0; ks < 4; ++ks) {
    const ushort_t* src = (ks < 2)
        ? vals_nhwc + ((long)bh * WW) * 64 + ks * 32
        : attn_nhwc + ((long)bh * WW) * 64 + (ks - 2) * 32;
    short8 afr[2];
    #pragma unroll
    for (int mf = 0; mf < 2; ++mf) {
      const int pix = w0 + mf * 16 + row16;
      afr[mf] = *(const short8*)(src + (long)pix * 64 + kg * 8);
    }
    #pragma unroll
    for (int nf = 0; nf < 4; ++nf) {
      const short8 bfr =
          *(const short8*)(packedA + ((long)(ks * 4 + nf) * 64 + l) * 8);
      acc[0][nf] = __builtin_amdgcn_mfma_f32_16x16x32_bf16(
          afr[0], bfr, acc[0][nf], 0, 0, 0);
      acc[1][nf] = __builtin_amdgcn_mfma_f32_16x16x32_bf16(
          afr[1], bfr, acc[1][nf], 0, 0, 0);
    }
  }

  #pragma unroll
  for (int mf = 0; mf < 2; ++mf)
    #pragma unroll
    for (int nf = 0; nf < 4; ++nf)
      #pragma unroll
      for (int r = 0; r < 4; ++r) {
        const int pix = w0 + mf * 16 + kg * 4 + r;
        const int cch = nf * 16 + row16;
        float o = acc[mf][nf][r] + b_attn[cch];
        o = (o >= 0.f) ? o : 0.2f * o;
        out_lds[pix * 65 + cch] = o;
      }
  __syncthreads();

  #pragma unroll
  for (int i = 0; i < 32; ++i) {
    const int idx = tid + i * 256;
    const int cch = idx >> 7, wp = idx & 127;
    out[((long)(b * ENC_C + cch) * HH + h) * WW + wp] = out_lds[wp * 65 + cch];
  }
}

// ---------------------------------------------------------------------------
extern "C" void kernel_launch(void* const* d_in, const int* in_sizes, int n_in,
                              void* d_out, int out_size, void* d_ws, size_t ws_size,
                              hipStream_t stream) {
  const float* enc    = (const float*)d_in[0];
  const float* dec    = (const float*)d_in[1];
  const float* W_enc  = (const float*)d_in[2];
  const float* b_enc  = (const float*)d_in[3];
  const float* W_dec  = (const float*)d_in[4];
  const float* b_dec  = (const float*)d_in[5];
  const float* W_agg  = (const float*)d_in[6];
  const float* b_agg  = (const float*)d_in[7];
  const float* W_attn = (const float*)d_in[8];
  const float* b_attn = (const float*)d_in[9];
  const float* conv_w = (const float*)d_in[10];
  const float* conv_b = (const float*)d_in[11];
  float* out = (float*)d_out;

  const long npix = (long)BB * HH * WW;               // 131072
  float* q_chw      = (float*)d_ws;                   // [B][64][H][W] f32
  float* k_chw      = q_chw + npix * 64;              // [B][64][H][W] f32
  ushort_t* dec_t   = (ushort_t*)(k_chw + npix * 64); // [npix][128] bf16
  ushort_t* vals    = dec_t + npix * 128;             // [npix][64] bf16
  ushort_t* attn    = vals + npix * 64;               // [npix][64] bf16
  ushort_t* packedC = attn + npix * 64;               // conv W frags (144 blocks)
  ushort_t* packedA = packedC + 144 * 64 * 8;         // W_attn frags (16)
  ushort_t* packedQ = packedA + 16 * 64 * 8;          // W_dec frags (16)
  ushort_t* packedK = packedQ + 16 * 64 * 8;          // W_enc frags (8)

  hipLaunchKernelGGL(pack_w_kernel, dim3(184), dim3(64), 0, stream,
                     conv_w, W_attn, W_dec, W_enc, packedC, packedA, packedQ, packedK);
  hipLaunchKernelGGL(prep_kernel, dim3(BB * HH), dim3(256), 0, stream,
                     enc, dec, packedQ, packedK, b_enc, b_dec, q_chw, k_chw, dec_t);
  hipLaunchKernelGGL(conv_mfma_kernel, dim3(BB * HH), dim3(256), 0, stream,
                     dec_t, packedC, conv_b, vals);
  hipLaunchKernelGGL(attn_kernel, dim3(BB * HH / 2), dim3(256), 0, stream,
                     q_chw, k_chw, enc, W_agg, b_agg, attn);
  hipLaunchKernelGGL(out_kernel, dim3(BB * HH), dim3(256), 0, stream,
                     vals, attn, packedA, b_attn, out);
}

// Round 5
// 158.420 us; speedup vs baseline: 7.4159x; 1.1102x over previous
//
#include <hip/hip_runtime.h>

#define BB 8
#define ENC_C 64
#define DEC_C 128
#define HH 128
#define WW 128

typedef unsigned short ushort_t;
typedef __attribute__((ext_vector_type(8))) short short8;
typedef __attribute__((ext_vector_type(4))) short short4v;
typedef __attribute__((ext_vector_type(4))) float f32x4;

static __device__ __forceinline__ ushort_t f2bf(float x) {
  unsigned int u = __builtin_bit_cast(unsigned int, x);
  u += 0x7fff + ((u >> 16) & 1);   // round-to-nearest-even
  return (ushort_t)(u >> 16);
}
static __device__ __forceinline__ float bf2f(ushort_t v) {
  unsigned int u = ((unsigned int)v) << 16;
  return __builtin_bit_cast(float, u);
}

// ---------------------------------------------------------------------------
// Kernel 0: pack weight fragments (bf16) for all four matmuls.
//   blk 0..143   : conv_w (K=1152)  -> packedC   (used as B operand)
//   blk 144..159 : W_attn (K=128)   -> packedA   (used as A operand, swapped)
//   blk 160..175 : W_dec  (K=128)   -> packedQ   (A operand, swapped)
//   blk 176..183 : W_enc  (K=64)    -> packedK   (A operand, swapped)
// Frag: lane l, elem j holds W[k = ks*32 + (l>>4)*8 + j][n = nf*16 + (l&15)].
// (A-frag row=l&15 and B-frag col=l&15 share this exact layout.)
// ---------------------------------------------------------------------------
__global__ __launch_bounds__(64) void pack_w_kernel(
    const float* __restrict__ conv_w, const float* __restrict__ W_attn,
    const float* __restrict__ W_dec, const float* __restrict__ W_enc,
    ushort_t* __restrict__ packedC, ushort_t* __restrict__ packedA,
    ushort_t* __restrict__ packedQ, ushort_t* __restrict__ packedK)
{
  const int blk = blockIdx.x;
  const int l = threadIdx.x;
  const float* W;
  ushort_t* dst;
  int bb;
  if (blk < 144) {
    const int kstep = blk >> 2, nf = blk & 3;
    const int tap = kstep >> 2, dstep = kstep & 3;
    const int n = nf * 16 + (l & 15);
    const int dbase = dstep * 32 + (l >> 4) * 8;
    ushort_t v[8];
    #pragma unroll
    for (int j = 0; j < 8; ++j)
      v[j] = f2bf(conv_w[(tap * DEC_C + dbase + j) * 64 + n]);
    ushort_t* d = packedC + ((long)blk * 64 + l) * 8;
    #pragma unroll
    for (int j = 0; j < 8; ++j) d[j] = v[j];
    return;
  } else if (blk < 160) {
    W = W_attn; dst = packedA; bb = blk - 144;
  } else if (blk < 176) {
    W = W_dec;  dst = packedQ; bb = blk - 160;
  } else {
    W = W_enc;  dst = packedK; bb = blk - 176;
  }
  const int ks = bb >> 2, nf = bb & 3;
  const int n = nf * 16 + (l & 15);
  const int kbase = ks * 32 + (l >> 4) * 8;
  ushort_t v[8];
  #pragma unroll
  for (int j = 0; j < 8; ++j)
    v[j] = f2bf(W[(kbase + j) * 64 + n]);
  ushort_t* d = dst + ((long)bb * 64 + l) * 8;
  #pragma unroll
  for (int j = 0; j < 8; ++j) d[j] = v[j];
}

// ---------------------------------------------------------------------------
// Kernel 1: per (b,h) row. Swapped MFMA: D = W^T (A) x tile^T (B) lands in
// (channel, pixel) order -> direct CHW bf16 stores, no transpose epilogue.
// LDS tile [w][c] f32 stride 68 -> B-frags = 2x ds_read_b128.
// Outputs: q_bf, k_bf (CHW bf16, bias added), dec_t (NHWC bf16).
// ---------------------------------------------------------------------------
__global__ __launch_bounds__(256) void prep_kernel(
    const float* __restrict__ enc, const float* __restrict__ dec,
    const ushort_t* __restrict__ packedQ, const ushort_t* __restrict__ packedK,
    const float* __restrict__ b_enc, const float* __restrict__ b_dec,
    ushort_t* __restrict__ q_bf, ushort_t* __restrict__ k_bf,
    ushort_t* __restrict__ dec_t)
{
  __shared__ float smem[WW * 68];
  const int bh = blockIdx.x;
  const int b = bh >> 7, h = bh & 127;
  const int tid = threadIdx.x;
  const int l = tid & 63;
  const int wv = tid >> 6;
  const int pix0 = wv * 32;
  const int col = l & 15, kg = l >> 4;

  // ---- encoder tile [w][c] ----
  #pragma unroll
  for (int i = 0; i < 32; ++i) {
    int idx = tid + i * 256;
    int cc = idx >> 7, wl = idx & 127;
    smem[wl * 68 + cc] = enc[((b * ENC_C + cc) * HH + h) * WW + wl];
  }
  __syncthreads();

  // k^T = W_enc^T x enc^T
  f32x4 acck[4][2];
  #pragma unroll
  for (int mf = 0; mf < 4; ++mf)
    #pragma unroll
    for (int pf = 0; pf < 2; ++pf)
      acck[mf][pf] = (f32x4){0.f, 0.f, 0.f, 0.f};

  #pragma unroll
  for (int ks = 0; ks < 2; ++ks) {
    short8 bfr[2];
    #pragma unroll
    for (int pf = 0; pf < 2; ++pf) {
      const int pix = pix0 + pf * 16 + col;
      const float4* p =
          (const float4*)&smem[pix * 68 + ks * 32 + kg * 8];
      float4 x0 = p[0], x1 = p[1];
      short8 v;
      v[0] = (short)f2bf(x0.x); v[1] = (short)f2bf(x0.y);
      v[2] = (short)f2bf(x0.z); v[3] = (short)f2bf(x0.w);
      v[4] = (short)f2bf(x1.x); v[5] = (short)f2bf(x1.y);
      v[6] = (short)f2bf(x1.z); v[7] = (short)f2bf(x1.w);
      bfr[pf] = v;
    }
    #pragma unroll
    for (int mf = 0; mf < 4; ++mf) {
      const short8 afr =
          *(const short8*)(packedK + ((long)(ks * 4 + mf) * 64 + l) * 8);
      #pragma unroll
      for (int pf = 0; pf < 2; ++pf)
        acck[mf][pf] = __builtin_amdgcn_mfma_f32_16x16x32_bf16(
            afr, bfr[pf], acck[mf][pf], 0, 0, 0);
    }
  }
  // store k (CHW bf16)
  #pragma unroll
  for (int mf = 0; mf < 4; ++mf)
    #pragma unroll
    for (int pf = 0; pf < 2; ++pf)
      #pragma unroll
      for (int r = 0; r < 4; ++r) {
        const int n = mf * 16 + kg * 4 + r;
        const int pix = pix0 + pf * 16 + col;
        k_bf[((long)(b * ENC_C + n) * HH + h) * WW + pix] =
            f2bf(acck[mf][pf][r] + b_enc[n]);
      }
  __syncthreads();

  // ---- decoder tile, two 64-channel halves ----
  f32x4 accq[4][2];
  #pragma unroll
  for (int mf = 0; mf < 4; ++mf)
    #pragma unroll
    for (int pf = 0; pf < 2; ++pf)
      accq[mf][pf] = (f32x4){0.f, 0.f, 0.f, 0.f};

  #pragma unroll
  for (int hf = 0; hf < 2; ++hf) {
    #pragma unroll
    for (int i = 0; i < 32; ++i) {
      int idx = tid + i * 256;
      int cc = idx >> 7, wl = idx & 127;
      smem[wl * 68 + cc] = dec[((b * DEC_C + hf * 64 + cc) * HH + h) * WW + wl];
    }
    __syncthreads();

    // dec_t NHWC bf16 (conv A-operand)
    #pragma unroll
    for (int i = 0; i < 32; ++i) {
      int idx = tid + i * 256;
      int wl = idx >> 6, cc = idx & 63;
      dec_t[((long)bh * WW + wl) * DEC_C + hf * 64 + cc] =
          f2bf(smem[wl * 68 + cc]);
    }

    #pragma unroll
    for (int ks2 = 0; ks2 < 2; ++ks2) {
      const int ks = hf * 2 + ks2;
      short8 bfr[2];
      #pragma unroll
      for (int pf = 0; pf < 2; ++pf) {
        const int pix = pix0 + pf * 16 + col;
        const float4* p =
            (const float4*)&smem[pix * 68 + ks2 * 32 + kg * 8];
        float4 x0 = p[0], x1 = p[1];
        short8 v;
        v[0] = (short)f2bf(x0.x); v[1] = (short)f2bf(x0.y);
        v[2] = (short)f2bf(x0.z); v[3] = (short)f2bf(x0.w);
        v[4] = (short)f2bf(x1.x); v[5] = (short)f2bf(x1.y);
        v[6] = (short)f2bf(x1.z); v[7] = (short)f2bf(x1.w);
        bfr[pf] = v;
      }
      #pragma unroll
      for (int mf = 0; mf < 4; ++mf) {
        const short8 afr =
            *(const short8*)(packedQ + ((long)(ks * 4 + mf) * 64 + l) * 8);
        #pragma unroll
        for (int pf = 0; pf < 2; ++pf)
          accq[mf][pf] = __builtin_amdgcn_mfma_f32_16x16x32_bf16(
              afr, bfr[pf], accq[mf][pf], 0, 0, 0);
      }
    }
    __syncthreads();
  }

  // store q (CHW bf16)
  #pragma unroll
  for (int mf = 0; mf < 4; ++mf)
    #pragma unroll
    for (int pf = 0; pf < 2; ++pf)
      #pragma unroll
      for (int r = 0; r < 4; ++r) {
        const int n = mf * 16 + kg * 4 + r;
        const int pix = pix0 + pf * 16 + col;
        q_bf[((long)(b * ENC_C + n) * HH + h) * WW + pix] =
            f2bf(accq[mf][pf][r] + b_dec[n]);
      }
}

// ---------------------------------------------------------------------------
// Kernel 2: attention, lane = pixel. q/k CHW bf16, enc NCHW f32.
// Output attn_vec NHWC bf16 via LDS transpose.
// ---------------------------------------------------------------------------
__global__ __launch_bounds__(256) void attn_kernel(
    const ushort_t* __restrict__ q_bf, const ushort_t* __restrict__ k_bf,
    const float* __restrict__ enc, const float* __restrict__ W_agg,
    const float* __restrict__ b_agg, ushort_t* __restrict__ attn_nhwc)
{
  __shared__ ushort_t att_lds[2][64][130];
  const int half = threadIdx.x >> 7;
  const int w = threadIdx.x & 127;
  const int bh = blockIdx.x * 2 + half;
  const int b = bh >> 7, h = bh & 127;

  int off[9]; float s[9]; bool valid[9];
  #pragma unroll
  for (int n = 0; n < 9; ++n) {
    const int dh = n / 3 - 1, dw = n % 3 - 1;
    const int nh = h + dh, nw = w + dw;
    valid[n] = (nh >= 0 && nh < HH && nw >= 0 && nw < WW);
    const int nhc = min(max(nh, 0), HH - 1);
    const int nwc = min(max(nw, 0), WW - 1);
    off[n] = nhc * WW + nwc;           // clamped: loads always in-bounds
    s[n] = 0.f;
  }

  const long plane = (long)HH * WW;
  const ushort_t* qp = q_bf + ((long)(b * ENC_C) * HH + h) * WW + w;
  const ushort_t* kp = k_bf + (long)(b * ENC_C) * plane;
  const float* ep = enc + (long)(b * ENC_C) * plane;
  const float bagg = b_agg[0];

  // pass 1: scores
  for (int c = 0; c < 64; ++c) {
    const float qv = bf2f(qp[(long)c * plane]);
    const float wac = W_agg[c];                  // wave-uniform -> s_load
    const ushort_t* kc = kp + (long)c * plane;
    #pragma unroll
    for (int n = 0; n < 9; ++n) {
      float x = qv + bf2f(kc[off[n]]);
      x = fminf(fmaxf(x, -15.f), 15.f);
      float z = __builtin_amdgcn_exp2f(x * 2.88539008f);  // e^(2x)
      float t = __builtin_fmaf(-2.f, __builtin_amdgcn_rcpf(z + 1.f), 1.f);
      s[n] += t * wac;
    }
  }

  // softmax over valid neighbors
  float m = -1e30f;
  #pragma unroll
  for (int n = 0; n < 9; ++n) {
    s[n] = valid[n] ? (s[n] + bagg) : -1e30f;
    m = fmaxf(m, s[n]);
  }
  float attw[9]; float denom = 0.f;
  #pragma unroll
  for (int n = 0; n < 9; ++n) {
    attw[n] = __builtin_amdgcn_exp2f((s[n] - m) * 1.44269504f);
    denom += attw[n];
  }
  const float inv = __builtin_amdgcn_rcpf(denom);
  #pragma unroll
  for (int n = 0; n < 9; ++n) attw[n] *= inv;   // invalid -> exactly 0

  // pass 2: weighted encoder-neighbor sum, per channel
  for (int c = 0; c < 64; ++c) {
    const float* ec = ep + (long)c * plane;
    float a = 0.f;
    #pragma unroll
    for (int n = 0; n < 9; ++n) a += attw[n] * ec[off[n]];
    att_lds[half][c][w] = f2bf(a);
  }
  __syncthreads();

  // transposed NHWC bf16 store (coalesced)
  const int c2 = w & 63;
  const int sub = w >> 6;
  #pragma unroll
  for (int i = 0; i < 64; ++i) {
    const int wp = i * 2 + sub;
    attn_nhwc[((long)bh * WW + wp) * 64 + c2] = att_lds[half][c2][wp];
  }
}

// ---------------------------------------------------------------------------
// Kernel 3: fused conv(3x3, MFMA) + out = LeakyReLU([vals;attn]@W_attn + b).
// Conv acc -> LDS bf16 [pix][c] (stride 68) -> out MFMA (swapped: D in
// (channel, pixel) order) -> direct coalesced NCHW f32 stores. No vals
// global round-trip, no output-transpose LDS.
// ---------------------------------------------------------------------------
__global__ __launch_bounds__(256) void conv_out_kernel(
    const ushort_t* __restrict__ dec_t, const ushort_t* __restrict__ packedC,
    const float* __restrict__ conv_b, const ushort_t* __restrict__ attn_nhwc,
    const ushort_t* __restrict__ packedA, const float* __restrict__ b_attn,
    float* __restrict__ out)
{
  __shared__ ushort_t vlds[WW * 68];
  const int bh = blockIdx.x;
  const int b = bh >> 7, h = bh & 127;
  const int tid = threadIdx.x;
  const int l = tid & 63;
  const int wv = tid >> 6;
  const int pix0 = wv * 32;
  const int col = l & 15, kg = l >> 4;

  // ---- conv phase (A = pixels from dec_t, B = packedC weights) ----
  f32x4 acc[2][4];
  #pragma unroll
  for (int mf = 0; mf < 2; ++mf)
    #pragma unroll
    for (int nf = 0; nf < 4; ++nf)
      acc[mf][nf] = (f32x4){0.f, 0.f, 0.f, 0.f};

  #pragma unroll
  for (int kh = 0; kh < 3; ++kh) {
    const int hh = h + kh - 1;
    if (hh < 0 || hh >= HH) continue;   // block-uniform skip
    const ushort_t* arow = dec_t + ((long)(b * HH + hh) * WW) * DEC_C;
    #pragma unroll
    for (int kw = 0; kw < 3; ++kw) {
      const int tap = kh * 3 + kw;
      #pragma unroll
      for (int ds = 0; ds < 4; ++ds) {
        const int d0 = ds * 32;
        short8 afr[2];
        #pragma unroll
        for (int mf = 0; mf < 2; ++mf) {
          const int wp = pix0 + mf * 16 + col + kw - 1;
          short8 v = {0, 0, 0, 0, 0, 0, 0, 0};
          if (wp >= 0 && wp < WW)
            v = *(const short8*)(arow + (long)wp * DEC_C + d0 + kg * 8);
          afr[mf] = v;
        }
        const int kstep = tap * 4 + ds;
        #pragma unroll
        for (int nf = 0; nf < 4; ++nf) {
          const short8 bfr =
              *(const short8*)(packedC + ((long)(kstep * 4 + nf) * 64 + l) * 8);
          acc[0][nf] = __builtin_amdgcn_mfma_f32_16x16x32_bf16(
              afr[0], bfr, acc[0][nf], 0, 0, 0);
          acc[1][nf] = __builtin_amdgcn_mfma_f32_16x16x32_bf16(
              afr[1], bfr, acc[1][nf], 0, 0, 0);
        }
      }
    }
  }

  // vals -> LDS bf16 [pix][c] stride 68
  #pragma unroll
  for (int mf = 0; mf < 2; ++mf)
    #pragma unroll
    for (int nf = 0; nf < 4; ++nf)
      #pragma unroll
      for (int r = 0; r < 4; ++r) {
        const int pix = pix0 + mf * 16 + kg * 4 + r;
        const int c = nf * 16 + col;
        vlds[pix * 68 + c] = f2bf(acc[mf][nf][r] + conv_b[c]);
      }
  __syncthreads();

  // ---- out phase (swapped: A = W_attn^T frags, B = cat^T) ----
  f32x4 ao[4][2];
  #pragma unroll
  for (int mf = 0; mf < 4; ++mf)
    #pragma unroll
    for (int pf = 0; pf < 2; ++pf)
      ao[mf][pf] = (f32x4){0.f, 0.f, 0.f, 0.f};

  #pragma unroll
  for (int ks = 0; ks < 4; ++ks) {
    short8 bfr[2];
    #pragma unroll
    for (int pf = 0; pf < 2; ++pf) {
      const int pix = pix0 + pf * 16 + col;
      short8 v;
      if (ks < 2) {
        const int k0 = ks * 32 + kg * 8;
        short4v a0 = *(const short4v*)&vlds[pix * 68 + k0];
        short4v a1 = *(const short4v*)&vlds[pix * 68 + k0 + 4];
        v[0] = a0[0]; v[1] = a0[1]; v[2] = a0[2]; v[3] = a0[3];
        v[4] = a1[0]; v[5] = a1[1]; v[6] = a1[2]; v[7] = a1[3];
      } else {
        v = *(const short8*)(attn_nhwc + ((long)bh * WW + pix) * 64 +
                             (ks - 2) * 32 + kg * 8);
      }
      bfr[pf] = v;
    }
    #pragma unroll
    for (int mf = 0; mf < 4; ++mf) {
      const short8 afr =
          *(const short8*)(packedA + ((long)(ks * 4 + mf) * 64 + l) * 8);
      #pragma unroll
      for (int pf = 0; pf < 2; ++pf)
        ao[mf][pf] = __builtin_amdgcn_mfma_f32_16x16x32_bf16(
            afr, bfr[pf], ao[mf][pf], 0, 0, 0);
    }
  }

  // direct NCHW f32 stores (lanes 0-15 -> consecutive pix, 64B segments)
  #pragma unroll
  for (int mf = 0; mf < 4; ++mf)
    #pragma unroll
    for (int pf = 0; pf < 2; ++pf)
      #pragma unroll
      for (int r = 0; r < 4; ++r) {
        const int n = mf * 16 + kg * 4 + r;
        const int pix = pix0 + pf * 16 + col;
        float o = ao[mf][pf][r] + b_attn[n];
        o = (o >= 0.f) ? o : 0.2f * o;
        out[((long)(b * ENC_C + n) * HH + h) * WW + pix] = o;
      }
}

// ---------------------------------------------------------------------------
extern "C" void kernel_launch(void* const* d_in, const int* in_sizes, int n_in,
                              void* d_out, int out_size, void* d_ws, size_t ws_size,
                              hipStream_t stream) {
  const float* enc    = (const float*)d_in[0];
  const float* dec    = (const float*)d_in[1];
  const float* W_enc  = (const float*)d_in[2];
  const float* b_enc  = (const float*)d_in[3];
  const float* W_dec  = (const float*)d_in[4];
  const float* b_dec  = (const float*)d_in[5];
  const float* W_agg  = (const float*)d_in[6];
  const float* b_agg  = (const float*)d_in[7];
  const float* W_attn = (const float*)d_in[8];
  const float* b_attn = (const float*)d_in[9];
  const float* conv_w = (const float*)d_in[10];
  const float* conv_b = (const float*)d_in[11];
  float* out = (float*)d_out;

  const long npix = (long)BB * HH * WW;               // 131072
  ushort_t* q_bf    = (ushort_t*)d_ws;                // [B][64][H][W] bf16
  ushort_t* k_bf    = q_bf + npix * 64;               // [B][64][H][W] bf16
  ushort_t* dec_t   = k_bf + npix * 64;               // [npix][128] bf16
  ushort_t* att     = dec_t + npix * 128;             // [npix][64]  bf16
  ushort_t* packedC = att + npix * 64;                // conv W frags (144 blk)
  ushort_t* packedA = packedC + 144 * 64 * 8;         // W_attn frags (16)
  ushort_t* packedQ = packedA + 16 * 64 * 8;          // W_dec frags (16)
  ushort_t* packedK = packedQ + 16 * 64 * 8;          // W_enc frags (8)

  hipLaunchKernelGGL(pack_w_kernel, dim3(184), dim3(64), 0, stream,
                     conv_w, W_attn, W_dec, W_enc, packedC, packedA, packedQ, packedK);
  hipLaunchKernelGGL(prep_kernel, dim3(BB * HH), dim3(256), 0, stream,
                     enc, dec, packedQ, packedK, b_enc, b_dec, q_bf, k_bf, dec_t);
  hipLaunchKernelGGL(attn_kernel, dim3(BB * HH / 2), dim3(256), 0, stream,
                     q_bf, k_bf, enc, W_agg, b_agg, att);
  hipLaunchKernelGGL(conv_out_kernel, dim3(BB * HH), dim3(256), 0, stream,
                     dec_t, packedC, conv_b, att, packedA, b_attn, out);
}